// Round 2
// baseline (15590.807 us; speedup 1.0000x reference)
//
#include <hip/hip_runtime.h>
#include <hip/hip_bf16.h>

#define N_ROWS 65536
#define DIM 64
#define KC 2048
#define DECAY_F 0.99f
#define OMD_F 0.01f
#define EPS_F 1e-5f

// ws layout (floats):
static constexpr size_t WS_E2     = 0;                  // [2048]
static constexpr size_t WS_COUNTS = 2048;               // [2048]
static constexpr size_t WS_ESUM   = 4096;               // [2048*64]
static constexpr size_t WS_LOSS   = 4096 + 131072;      // [1]
static constexpr size_t WS_SMOOTH = WS_LOSS + 1;        // [2048]
static constexpr size_t WS_FLOATS = WS_SMOOTH + 2048;

#define TILE_C 8                 // codes per LDS tile
#define BUF_F  528               // 8*64 emb + 8 e2 + pad (floats)
#define KSLICE (KC / 4)          // codes per wave
#define NTILES (KSLICE / TILE_C) // 64 tiles per wave

__global__ void vq_e2_kernel(const float* __restrict__ embed, float* __restrict__ ws) {
    int k = blockIdx.x * blockDim.x + threadIdx.x;
    if (k >= KC) return;
    const float4* e4 = reinterpret_cast<const float4*>(embed + (size_t)k * DIM);
    float s = 0.f;
#pragma unroll
    for (int i = 0; i < DIM / 4; ++i) {
        float4 v = e4[i];
        s += v.x * v.x + v.y * v.y + v.z * v.z + v.w * v.w;
    }
    ws[WS_E2 + k] = s;
}

__global__ __launch_bounds__(256, 4) void vq_main_kernel(
    const float* __restrict__ x,
    const float* __restrict__ embed,
    float* __restrict__ ws,
    float* __restrict__ out_q,
    float* __restrict__ out_ind) {
    // Wave-private double-buffered embed tiles: no __syncthreads in main loop.
    __shared__ float lds_tile[4][2][BUF_F];
    __shared__ float s_dist[4][64];
    __shared__ int   s_idx[4][64];

    const int lane = threadIdx.x & 63;
    const int wave = __builtin_amdgcn_readfirstlane(threadIdx.x >> 6);
    const int row  = blockIdx.x * 64 + lane;

    // x row in registers (64 VGPRs)
    float xr[DIM];
    {
        const float4* x4 = reinterpret_cast<const float4*>(x + (size_t)row * DIM);
#pragma unroll
        for (int i = 0; i < DIM / 4; ++i) {
            float4 v = x4[i];
            xr[4 * i + 0] = v.x; xr[4 * i + 1] = v.y;
            xr[4 * i + 2] = v.z; xr[4 * i + 3] = v.w;
        }
    }

    const float* __restrict__ e2g = ws + WS_E2;
    const int k0 = wave * KSLICE;

    float* buf0 = &lds_tile[wave][0][0];
    float* buf1 = &lds_tile[wave][1][0];

    float best = __builtin_inff();
    int bidx = 0;

    // ---- prologue: stage tile 0 ----
    {
        const float* gsrc = embed + (size_t)k0 * DIM + lane * 8;
        float4 r0 = reinterpret_cast<const float4*>(gsrc)[0];
        float4 r1 = reinterpret_cast<const float4*>(gsrc)[1];
        float re2 = (lane < TILE_C) ? e2g[k0 + lane] : 0.f;
        float4* dst = reinterpret_cast<float4*>(buf0 + lane * 8);
        dst[0] = r0; dst[1] = r1;
        if (lane < TILE_C) buf0[TILE_C * DIM + lane] = re2;
    }

    for (int t = 0; t < NTILES; ++t) {
        float* cur = (t & 1) ? buf1 : buf0;
        float* nxt = (t & 1) ? buf0 : buf1;

        // issue next tile's global loads early (stay in flight during compute)
        float4 r0, r1; float re2 = 0.f;
        const bool have_next = (t + 1 < NTILES);
        if (have_next) {
            const float* gsrc = embed + (size_t)(k0 + (t + 1) * TILE_C) * DIM + lane * 8;
            r0 = reinterpret_cast<const float4*>(gsrc)[0];
            r1 = reinterpret_cast<const float4*>(gsrc)[1];
            if (lane < TILE_C) re2 = e2g[k0 + (t + 1) * TILE_C + lane];
        }

        // compute current tile: 8 codes, broadcast ds_read_b128
        const int kbase = k0 + t * TILE_C;
#pragma unroll
        for (int c = 0; c < TILE_C; ++c) {
            const float4* ep = reinterpret_cast<const float4*>(cur + c * DIM);
            float a0 = 0.f, a1 = 0.f, a2 = 0.f, a3 = 0.f;
#pragma unroll
            for (int q = 0; q < DIM / 4; ++q) {
                float4 e = ep[q];
                a0 = fmaf(xr[4 * q + 0], e.x, a0);
                a1 = fmaf(xr[4 * q + 1], e.y, a1);
                a2 = fmaf(xr[4 * q + 2], e.z, a2);
                a3 = fmaf(xr[4 * q + 3], e.w, a3);
            }
            float dot = (a0 + a1) + (a2 + a3);
            float dist = fmaf(-2.f, dot, cur[TILE_C * DIM + c]);
            if (dist < best) { best = dist; bidx = kbase + c; }
        }

        // write next tile into the other buffer (wave-private, no barrier)
        if (have_next) {
            float4* dst = reinterpret_cast<float4*>(nxt + lane * 8);
            dst[0] = r0; dst[1] = r1;
            if (lane < TILE_C) nxt[TILE_C * DIM + lane] = re2;
        }
    }

    s_dist[wave][lane] = best;
    s_idx[wave][lane]  = bidx;
    __syncthreads();

    // ---- epilogue: all 256 threads; 4 threads per row, 16 dims each ----
    {
        const int tid = threadIdx.x;
        const int r = tid >> 2;          // row within block
        const int p = tid & 3;           // dim quarter
        const int grow = blockIdx.x * 64 + r;

        float fb = s_dist[0][r];
        int   fi = s_idx[0][r];
#pragma unroll
        for (int w = 1; w < 4; ++w) {
            float dw = s_dist[w][r];
            int   iw = s_idx[w][r];
            if (dw < fb) { fb = dw; fi = iw; }
        }
        if (p == 0) out_ind[grow] = (float)fi;

        const float4* q4 = reinterpret_cast<const float4*>(embed + (size_t)fi * DIM + p * 16);
        const float4* x4 = reinterpret_cast<const float4*>(x + (size_t)grow * DIM + p * 16);
        float4* o4 = reinterpret_cast<float4*>(out_q + (size_t)grow * DIM + p * 16);
        float* esum = ws + WS_ESUM + (size_t)fi * DIM + p * 16;

        float loss = 0.f;
#pragma unroll
        for (int i = 0; i < 4; ++i) {
            float4 q = q4[i];
            float4 xv = x4[i];
            o4[i] = q;
            float d0 = q.x - xv.x; loss = fmaf(d0, d0, loss);
            float d1 = q.y - xv.y; loss = fmaf(d1, d1, loss);
            float d2 = q.z - xv.z; loss = fmaf(d2, d2, loss);
            float d3 = q.w - xv.w; loss = fmaf(d3, d3, loss);
            atomicAdd(&esum[4 * i + 0], xv.x);
            atomicAdd(&esum[4 * i + 1], xv.y);
            atomicAdd(&esum[4 * i + 2], xv.z);
            atomicAdd(&esum[4 * i + 3], xv.w);
        }
        if (p == 0) atomicAdd(&ws[WS_COUNTS + fi], 1.0f);

        // block loss reduction: per-wave shuffle, then one atomic per wave
#pragma unroll
        for (int off = 32; off > 0; off >>= 1)
            loss += __shfl_down(loss, off, 64);
        if (lane == 0) atomicAdd(&ws[WS_LOSS], loss);
    }
}

__global__ void vq_finalize1_kernel(const float* __restrict__ cluster_size,
                                    float* __restrict__ ws,
                                    float* __restrict__ out_loss) {
    __shared__ float red[256];
    const int t = threadIdx.x;
    float partial = 0.f;
    for (int k = t; k < KC; k += 256) {
        float ncs = fmaf(OMD_F, ws[WS_COUNTS + k], DECAY_F * cluster_size[k]);
        partial += ncs;
    }
    red[t] = partial;
    __syncthreads();
    for (int s = 128; s > 0; s >>= 1) {
        if (t < s) red[t] += red[t + s];
        __syncthreads();
    }
    const float n = red[0];
    const float denom = n + (float)(KC * 1e-5);
    for (int k = t; k < KC; k += 256) {
        float ncs = fmaf(OMD_F, ws[WS_COUNTS + k], DECAY_F * cluster_size[k]);
        ws[WS_SMOOTH + k] = (ncs + EPS_F) / denom * n;
    }
    if (t == 0) out_loss[0] = ws[WS_LOSS] / (float)((size_t)N_ROWS * DIM);
}

__global__ void vq_finalize2_kernel(const float* __restrict__ embed_avg,
                                    const float* __restrict__ ws,
                                    float* __restrict__ out_embed) {
    int i = blockIdx.x * blockDim.x + threadIdx.x;
    if (i >= KC * DIM) return;
    int k = i >> 6;
    float na = fmaf(OMD_F, ws[WS_ESUM + i], DECAY_F * embed_avg[i]);
    out_embed[i] = na / ws[WS_SMOOTH + k];
}

extern "C" void kernel_launch(void* const* d_in, const int* in_sizes, int n_in,
                              void* d_out, int out_size, void* d_ws, size_t ws_size,
                              hipStream_t stream) {
    const float* x            = (const float*)d_in[0];
    const float* embed        = (const float*)d_in[1];
    const float* embed_avg    = (const float*)d_in[2];
    const float* cluster_size = (const float*)d_in[3];

    float* out      = (float*)d_out;
    float* out_q    = out;                                  // [N*D]
    float* out_loss = out + (size_t)N_ROWS * DIM;           // [1]
    float* out_ind  = out_loss + 1;                         // [N]
    float* out_emb  = out_ind + N_ROWS;                     // [K*D]

    float* ws = (float*)d_ws;

    hipMemsetAsync(ws, 0, WS_FLOATS * sizeof(float), stream);
    vq_e2_kernel<<<KC / 256, 256, 0, stream>>>(embed, ws);
    vq_main_kernel<<<N_ROWS / 64, 256, 0, stream>>>(x, embed, ws, out_q, out_ind);
    vq_finalize1_kernel<<<1, 256, 0, stream>>>(cluster_size, ws, out_loss);
    vq_finalize2_kernel<<<(KC * DIM) / 256, 256, 0, stream>>>(embed_avg, ws, out_emb);
}

// Round 6
// 1194.333 us; speedup vs baseline: 13.0540x; 13.0540x over previous
//
#include <hip/hip_runtime.h>
#include <hip/hip_bf16.h>

#define N_ROWS 65536
#define DIM 64
#define KC 2048
#define KHALF 1024
#define TC 32                    // codes per LDS tile
#define NT (KHALF / TC)          // 32 tiles
#define DECAY_F 0.99f
#define OMD_F 0.01f
#define EPS_F 1e-5f

// ws layout (floats):
static constexpr size_t WS_E2     = 0;                       // [2048]
static constexpr size_t WS_COUNTS = 2048;                    // [2048]
static constexpr size_t WS_ESUM   = 4096;                    // [2048*64]
static constexpr size_t WS_LOSS   = 4096 + 131072;           // [1]  = 135168
static constexpr size_t WS_SMOOTH = WS_LOSS + 1;             // [2048] = 135169
static constexpr size_t WS_CAND   = 137218;                  // [2*65536] float2 (8B aligned)
static constexpr size_t WS_ZERO_BEG = WS_COUNTS;
static constexpr size_t WS_ZERO_CNT = (WS_LOSS + 1) - WS_COUNTS;  // counts+esum+loss

__global__ void vq_e2_kernel(const float* __restrict__ embed, float* __restrict__ ws) {
    int k = blockIdx.x * blockDim.x + threadIdx.x;
    if (k >= KC) return;
    const float4* e4 = reinterpret_cast<const float4*>(embed + (size_t)k * DIM);
    float s = 0.f;
#pragma unroll
    for (int i = 0; i < DIM / 4; ++i) {
        float4 v = e4[i];
        s += v.x * v.x + v.y * v.y + v.z * v.z + v.w * v.w;
    }
    ws[WS_E2 + k] = s;
}

// block: 256 rows x 1024 codes. 4 waves; wave -> 64 rows; lane = (row-slot, dim-half);
// each lane owns TWO rows (rowA, rowB=rowA+32) so one broadcast ds_read feeds 8 FMAs.
__global__ __launch_bounds__(256, 2) void vq_main_kernel(
    const float* __restrict__ x,
    const float* __restrict__ embed,
    float* __restrict__ ws) {
    __shared__ float tile[2][TC * DIM];    // 2 x 8 KB

    const int tid  = threadIdx.x;
    const int lane = tid & 63;
    const int wave = tid >> 6;
    const int rc   = blockIdx.x >> 1;      // 256 row-chunks
    const int kh   = blockIdx.x & 1;       // K half
    const int h    = lane & 1;             // dim half
    const int rw   = lane >> 1;            // row-slot within wave
    const int rowA = rc * 256 + wave * 64 + rw;
    const int rowB = rowA + 32;

    // two x half-rows in registers (64 VGPRs)
    float xa[32], xb[32];
    {
        const float4* a4 = reinterpret_cast<const float4*>(x + (size_t)rowA * DIM + h * 32);
        const float4* b4 = reinterpret_cast<const float4*>(x + (size_t)rowB * DIM + h * 32);
#pragma unroll
        for (int j = 0; j < 8; ++j) {
            float4 va = a4[j];
            xa[4 * j + 0] = va.x; xa[4 * j + 1] = va.y;
            xa[4 * j + 2] = va.z; xa[4 * j + 3] = va.w;
            float4 vb = b4[j];
            xb[4 * j + 0] = vb.x; xb[4 * j + 1] = vb.y;
            xb[4 * j + 2] = vb.z; xb[4 * j + 3] = vb.w;
        }
    }

    const float* __restrict__ e2p = ws + WS_E2 + kh * KHALF;
    const float* __restrict__ ebase = embed + (size_t)kh * KHALF * DIM;

    // stage tile t into buf: 8 KB = 8 segs x (64 lanes x 16 B); PER-LANE global addr!
#define STAGE(buf, t)                                                                         \
    {                                                                                         \
        const float* gsrc = ebase + (size_t)(t) * TC * DIM;                                   \
        _Pragma("unroll")                                                                     \
        for (int j = 0; j < 2; ++j) {                                                         \
            const int seg = j * 4 + wave;                                                     \
            __builtin_amdgcn_global_load_lds(                                                 \
                (const __attribute__((address_space(1))) void*)(gsrc + seg * 256 + lane * 4), \
                (__attribute__((address_space(3))) void*)(&tile[(buf)][seg * 256]),           \
                16, 0, 0);                                                                    \
        }                                                                                     \
    }

    STAGE(0, 0);
    __syncthreads();

    float bestA = __builtin_inff(), bestB = __builtin_inff();
    int   idxA = 0, idxB = 0;

    for (int t = 0; t < NT; ++t) {
        const int cur = t & 1;
        if (t + 1 < NT) STAGE(cur ^ 1, t + 1);

        const int kb = kh * KHALF + t * TC;
#pragma unroll
        for (int c = 0; c < TC; ++c) {
            const float4* ep = reinterpret_cast<const float4*>(&tile[cur][c * DIM + h * 32]);
            float a0 = 0.f, a1 = 0.f, a2 = 0.f, a3 = 0.f;
            float b0 = 0.f, b1 = 0.f, b2 = 0.f, b3 = 0.f;
#pragma unroll
            for (int j = 0; j < 8; ++j) {
                float4 e = ep[j];
                a0 = fmaf(xa[4 * j + 0], e.x, a0);
                a1 = fmaf(xa[4 * j + 1], e.y, a1);
                a2 = fmaf(xa[4 * j + 2], e.z, a2);
                a3 = fmaf(xa[4 * j + 3], e.w, a3);
                b0 = fmaf(xb[4 * j + 0], e.x, b0);
                b1 = fmaf(xb[4 * j + 1], e.y, b1);
                b2 = fmaf(xb[4 * j + 2], e.z, b2);
                b3 = fmaf(xb[4 * j + 3], e.w, b3);
            }
            float da = (a0 + a1) + (a2 + a3);
            float db = (b0 + b1) + (b2 + b3);
            da += __shfl_xor(da, 1, 64);          // pair-combine (DPP quad_perm)
            db += __shfl_xor(db, 1, 64);
            float e2c = e2p[t * TC + c];
            float dA = fmaf(-2.f, da, e2c);
            float dB = fmaf(-2.f, db, e2c);
            if (dA < bestA) { bestA = dA; idxA = kb + c; }
            if (dB < bestB) { bestB = dB; idxB = kb + c; }
        }
        __syncthreads();
    }
#undef STAGE

    if (h == 0) {
        float2* cand = reinterpret_cast<float2*>(ws + WS_CAND);
        cand[(size_t)kh * N_ROWS + rowA] = make_float2(bestA, (float)idxA);
        cand[(size_t)kh * N_ROWS + rowB] = make_float2(bestB, (float)idxB);
    }
}

// 64 rows/block, 4 threads/row (16 dims each): combine halves, gather, loss, EMA atomics.
__global__ __launch_bounds__(256) void vq_combine_kernel(
    const float* __restrict__ x,
    const float* __restrict__ embed,
    float* __restrict__ ws,
    float* __restrict__ out_q,
    float* __restrict__ out_ind) {
    const int tid = threadIdx.x;
    const int r = tid >> 2;
    const int p = tid & 3;
    const int row = blockIdx.x * 64 + r;

    const float2* cand = reinterpret_cast<const float2*>(ws + WS_CAND);
    float2 c0 = cand[row];
    float2 c1 = cand[(size_t)N_ROWS + row];
    int fi = (c1.x < c0.x) ? (int)c1.y : (int)c0.y;   // tie -> lower index (half 0)
    if (p == 0) out_ind[row] = (float)fi;

    const float4* q4 = reinterpret_cast<const float4*>(embed + (size_t)fi * DIM + p * 16);
    const float4* x4 = reinterpret_cast<const float4*>(x + (size_t)row * DIM + p * 16);
    float4* o4 = reinterpret_cast<float4*>(out_q + (size_t)row * DIM + p * 16);
    float* esum = ws + WS_ESUM + (size_t)fi * DIM + p * 16;

    float loss = 0.f;
#pragma unroll
    for (int i = 0; i < 4; ++i) {
        float4 q = q4[i];
        float4 xv = x4[i];
        o4[i] = q;
        float d0 = q.x - xv.x; loss = fmaf(d0, d0, loss);
        float d1 = q.y - xv.y; loss = fmaf(d1, d1, loss);
        float d2 = q.z - xv.z; loss = fmaf(d2, d2, loss);
        float d3 = q.w - xv.w; loss = fmaf(d3, d3, loss);
        atomicAdd(&esum[4 * i + 0], xv.x);
        atomicAdd(&esum[4 * i + 1], xv.y);
        atomicAdd(&esum[4 * i + 2], xv.z);
        atomicAdd(&esum[4 * i + 3], xv.w);
    }
    if (p == 0) atomicAdd(&ws[WS_COUNTS + fi], 1.0f);

#pragma unroll
    for (int off = 32; off > 0; off >>= 1)
        loss += __shfl_down(loss, off, 64);
    if ((tid & 63) == 0) atomicAdd(&ws[WS_LOSS], loss);
}

__global__ void vq_finalize1_kernel(const float* __restrict__ cluster_size,
                                    float* __restrict__ ws,
                                    float* __restrict__ out_loss) {
    __shared__ float red[256];
    const int t = threadIdx.x;
    float partial = 0.f;
    for (int k = t; k < KC; k += 256) {
        float ncs = fmaf(OMD_F, ws[WS_COUNTS + k], DECAY_F * cluster_size[k]);
        partial += ncs;
    }
    red[t] = partial;
    __syncthreads();
    for (int s = 128; s > 0; s >>= 1) {
        if (t < s) red[t] += red[t + s];
        __syncthreads();
    }
    const float n = red[0];
    const float denom = n + (float)(KC * 1e-5);
    for (int k = t; k < KC; k += 256) {
        float ncs = fmaf(OMD_F, ws[WS_COUNTS + k], DECAY_F * cluster_size[k]);
        ws[WS_SMOOTH + k] = (ncs + EPS_F) / denom * n;
    }
    if (t == 0) out_loss[0] = ws[WS_LOSS] / (float)((size_t)N_ROWS * DIM);
}

__global__ void vq_finalize2_kernel(const float* __restrict__ embed_avg,
                                    const float* __restrict__ ws,
                                    float* __restrict__ out_embed) {
    int i = blockIdx.x * blockDim.x + threadIdx.x;
    if (i >= KC * DIM) return;
    int k = i >> 6;
    float na = fmaf(OMD_F, ws[WS_ESUM + i], DECAY_F * embed_avg[i]);
    out_embed[i] = na / ws[WS_SMOOTH + k];
}

extern "C" void kernel_launch(void* const* d_in, const int* in_sizes, int n_in,
                              void* d_out, int out_size, void* d_ws, size_t ws_size,
                              hipStream_t stream) {
    const float* x            = (const float*)d_in[0];
    const float* embed        = (const float*)d_in[1];
    const float* embed_avg    = (const float*)d_in[2];
    const float* cluster_size = (const float*)d_in[3];

    float* out      = (float*)d_out;
    float* out_q    = out;                                  // [N*D]
    float* out_loss = out + (size_t)N_ROWS * DIM;           // [1]
    float* out_ind  = out_loss + 1;                         // [N]
    float* out_emb  = out_ind + N_ROWS;                     // [K*D]

    float* ws = (float*)d_ws;

    hipMemsetAsync(ws + WS_ZERO_BEG, 0, WS_ZERO_CNT * sizeof(float), stream);
    vq_e2_kernel<<<KC / 256, 256, 0, stream>>>(embed, ws);
    vq_main_kernel<<<(N_ROWS / 256) * 2, 256, 0, stream>>>(x, embed, ws);
    vq_combine_kernel<<<N_ROWS / 64, 256, 0, stream>>>(x, embed, ws, out_q, out_ind);
    vq_finalize1_kernel<<<1, 256, 0, stream>>>(cluster_size, ws, out_loss);
    vq_finalize2_kernel<<<(KC * DIM) / 256, 256, 0, stream>>>(embed_avg, ws, out_emb);
}

// Round 7
// 502.142 us; speedup vs baseline: 31.0486x; 2.3785x over previous
//
#include <hip/hip_runtime.h>
#include <hip/hip_bf16.h>

#define N_ROWS 65536
#define DIM 64
#define KC 2048
#define KQ 512                   // codes per K-quarter
#define TC 64                    // codes per LDS tile
#define NT (KQ / TC)             // 8 tiles
#define DECAY_F 0.99f
#define OMD_F 0.01f
#define EPS_F 1e-5f

// ws layout (float units):
static constexpr size_t WS_E2     = 0;                        // f32 [2048]
static constexpr size_t WS_SMOOTH = 2048;                     // f32 [2048]
static constexpr size_t WS_OFFS   = 4096;                     // i32 [2048]
static constexpr size_t WS_ROWIDS = 6144;                     // i32 [65536]
static constexpr size_t WS_CAND   = 71680;                    // f32 [4*65536*2] (float2, even ✓)
static constexpr size_t WS_COUNTS = 595968;                   // i32 [2048]  <- zero from here
static constexpr size_t WS_CURS   = 598016;                   // i32 [2048]
static constexpr size_t WS_LOSS   = 600064;                   // f32 [1]
static constexpr size_t WS_ZERO_BEG = WS_COUNTS;
static constexpr size_t WS_ZERO_CNT = (WS_LOSS + 1) - WS_COUNTS; // 4097

__global__ void vq_e2_kernel(const float* __restrict__ embed, float* __restrict__ ws) {
    int k = blockIdx.x * blockDim.x + threadIdx.x;
    if (k >= KC) return;
    const float4* e4 = reinterpret_cast<const float4*>(embed + (size_t)k * DIM);
    float s = 0.f;
#pragma unroll
    for (int i = 0; i < DIM / 4; ++i) {
        float4 v = e4[i];
        s += v.x * v.x + v.y * v.y + v.z * v.z + v.w * v.w;
    }
    ws[WS_E2 + k] = s;
}

// block: 512 rows x 512 codes (K-quarter). 4 waves; wave -> 128 rows.
// lane = (row-slot rw=lane>>1, dim-half h=lane&1); lane owns FOUR rows
// (+0,+32,+64,+96) so one broadcast ds_read_b128 feeds 16 FMAs.
__global__ __launch_bounds__(256, 2) void vq_main_kernel(
    const float* __restrict__ x,
    const float* __restrict__ embed,
    float* __restrict__ ws) {
    __shared__ float tile[2][TC * DIM];    // 2 x 16 KB

    const int tid  = threadIdx.x;
    const int lane = tid & 63;
    const int wave = tid >> 6;
    const int rc   = blockIdx.x >> 2;      // 128 row-chunks
    const int kq   = blockIdx.x & 3;       // K quarter
    const int h    = lane & 1;             // dim half
    const int rw   = lane >> 1;            // row-slot within wave
    const int base = rc * 512 + wave * 128 + rw;

    // four x half-rows in registers (128 VGPRs)
    float xr[4][32];
#pragma unroll
    for (int r = 0; r < 4; ++r) {
        const float4* a4 = reinterpret_cast<const float4*>(
            x + (size_t)(base + r * 32) * DIM + h * 32);
#pragma unroll
        for (int j = 0; j < 8; ++j) {
            float4 v = a4[j];
            xr[r][4 * j + 0] = v.x; xr[r][4 * j + 1] = v.y;
            xr[r][4 * j + 2] = v.z; xr[r][4 * j + 3] = v.w;
        }
    }

    const float* __restrict__ e2p = ws + WS_E2 + kq * KQ;
    const float* __restrict__ ebase = embed + (size_t)kq * KQ * DIM;

    // stage tile t (64 codes = 16 KB = 16 segs x (64 lanes x 16 B)); per-lane src!
#define STAGE(buf, t)                                                                         \
    {                                                                                         \
        const float* gsrc = ebase + (size_t)(t) * TC * DIM;                                   \
        _Pragma("unroll")                                                                     \
        for (int j = 0; j < 4; ++j) {                                                         \
            const int seg = j * 4 + wave;                                                     \
            __builtin_amdgcn_global_load_lds(                                                 \
                (const __attribute__((address_space(1))) void*)(gsrc + seg * 256 + lane * 4), \
                (__attribute__((address_space(3))) void*)(&tile[(buf)][seg * 256]),           \
                16, 0, 0);                                                                    \
        }                                                                                     \
    }

    STAGE(0, 0);
    __syncthreads();

    float best[4] = {__builtin_inff(), __builtin_inff(), __builtin_inff(), __builtin_inff()};
    int   bidx[4] = {0, 0, 0, 0};

    for (int t = 0; t < NT; ++t) {
        const int cur = t & 1;
        if (t + 1 < NT) STAGE(cur ^ 1, t + 1);

        const int kb = kq * KQ + t * TC;
#pragma unroll 4
        for (int c = 0; c < TC; ++c) {
            const float4* ep = reinterpret_cast<const float4*>(&tile[cur][c * DIM + h * 32]);
            float a0[4] = {0.f, 0.f, 0.f, 0.f};
            float a1[4] = {0.f, 0.f, 0.f, 0.f};
            float a2[4] = {0.f, 0.f, 0.f, 0.f};
            float a3[4] = {0.f, 0.f, 0.f, 0.f};
#pragma unroll
            for (int j = 0; j < 8; ++j) {
                float4 e = ep[j];
#pragma unroll
                for (int r = 0; r < 4; ++r) {
                    a0[r] = fmaf(xr[r][4 * j + 0], e.x, a0[r]);
                    a1[r] = fmaf(xr[r][4 * j + 1], e.y, a1[r]);
                    a2[r] = fmaf(xr[r][4 * j + 2], e.z, a2[r]);
                    a3[r] = fmaf(xr[r][4 * j + 3], e.w, a3[r]);
                }
            }
            float e2c = e2p[t * TC + c];
#pragma unroll
            for (int r = 0; r < 4; ++r) {
                float d = (a0[r] + a1[r]) + (a2[r] + a3[r]);
                d += __shfl_xor(d, 1, 64);        // pair-combine halves (DPP)
                float dist = fmaf(-2.f, d, e2c);
                if (dist < best[r]) { best[r] = dist; bidx[r] = kb + c; }
            }
        }
        __syncthreads();
    }
#undef STAGE

    if (h == 0) {
        float2* cand = reinterpret_cast<float2*>(ws + WS_CAND);
#pragma unroll
        for (int r = 0; r < 4; ++r)
            cand[(size_t)kq * N_ROWS + base + r * 32] = make_float2(best[r], (float)bidx[r]);
    }
}

// 64 rows/block, 4 threads/row (16 dims each): pick min of 4 quarters
// (ascending quarter order, strict < -> lowest index on ties), gather out_q,
// commit loss, count histogram. NO per-element scatter atomics.
__global__ __launch_bounds__(256) void vq_combine_kernel(
    const float* __restrict__ x,
    const float* __restrict__ embed,
    float* __restrict__ ws,
    float* __restrict__ out_q,
    float* __restrict__ out_ind) {
    const int tid = threadIdx.x;
    const int r = tid >> 2;
    const int p = tid & 3;
    const int row = blockIdx.x * 64 + r;

    const float2* cand = reinterpret_cast<const float2*>(ws + WS_CAND);
    float bb = __builtin_inff();
    int fi = 0;
#pragma unroll
    for (int q = 0; q < 4; ++q) {
        float2 c = cand[(size_t)q * N_ROWS + row];
        if (c.x < bb) { bb = c.x; fi = (int)c.y; }
    }
    if (p == 0) {
        out_ind[row] = (float)fi;
        atomicAdd((int*)(ws + WS_COUNTS) + fi, 1);
    }

    const float4* q4 = reinterpret_cast<const float4*>(embed + (size_t)fi * DIM + p * 16);
    const float4* x4 = reinterpret_cast<const float4*>(x + (size_t)row * DIM + p * 16);
    float4* o4 = reinterpret_cast<float4*>(out_q + (size_t)row * DIM + p * 16);

    float loss = 0.f;
#pragma unroll
    for (int i = 0; i < 4; ++i) {
        float4 q = q4[i];
        float4 xv = x4[i];
        o4[i] = q;
        float d0 = q.x - xv.x; loss = fmaf(d0, d0, loss);
        float d1 = q.y - xv.y; loss = fmaf(d1, d1, loss);
        float d2 = q.z - xv.z; loss = fmaf(d2, d2, loss);
        float d3 = q.w - xv.w; loss = fmaf(d3, d3, loss);
    }
#pragma unroll
    for (int off = 32; off > 0; off >>= 1)
        loss += __shfl_down(loss, off, 64);
    if ((tid & 63) == 0) atomicAdd(ws + WS_LOSS, loss);
}

// 1 block: exclusive prefix over counts -> offsets; laplace smoothing; loss.
__global__ __launch_bounds__(256) void vq_prefix_kernel(
    const float* __restrict__ cluster_size,
    float* __restrict__ ws,
    float* __restrict__ out_loss) {
    __shared__ int   sscan[256];
    __shared__ float sred[256];
    const int tid = threadIdx.x;
    const int* counts = (const int*)(ws + WS_COUNTS);
    int* offs = (int*)(ws + WS_OFFS);

    int lc[8];
    int tot = 0;
    float csum = 0.f;
#pragma unroll
    for (int j = 0; j < 8; ++j) {
        lc[j] = counts[tid * 8 + j];
        tot += lc[j];
        csum += cluster_size[tid * 8 + j];
    }
    sscan[tid] = tot;
    sred[tid] = csum;
    __syncthreads();
    for (int off = 1; off < 256; off <<= 1) {
        int v = (tid >= off) ? sscan[tid - off] : 0;
        __syncthreads();
        sscan[tid] += v;
        __syncthreads();
    }
    for (int s = 128; s > 0; s >>= 1) {
        if (tid < s) sred[tid] += sred[tid + s];
        __syncthreads();
    }
    int run = sscan[tid] - tot;      // exclusive prefix
#pragma unroll
    for (int j = 0; j < 8; ++j) {
        offs[tid * 8 + j] = run;
        run += lc[j];
    }
    // n = sum(0.99*cs + 0.01*counts) = 0.99*sum(cs) + 0.01*N
    const float n = DECAY_F * sred[0] + OMD_F * (float)N_ROWS;
    const float scale = n / (n + (float)KC * EPS_F);
#pragma unroll
    for (int j = 0; j < 8; ++j) {
        int k = tid * 8 + j;
        float ncs = fmaf(OMD_F, (float)counts[k], DECAY_F * cluster_size[k]);
        ws[WS_SMOOTH + k] = (ncs + EPS_F) * scale;
    }
    if (tid == 0) out_loss[0] = ws[WS_LOSS] / (float)((size_t)N_ROWS * DIM);
}

// bucket-fill: row ids grouped by code.
__global__ __launch_bounds__(256) void vq_fill_kernel(
    const float* __restrict__ out_ind,
    float* __restrict__ ws) {
    const int row = blockIdx.x * blockDim.x + threadIdx.x;
    const int fi = (int)out_ind[row];
    const int* offs = (const int*)(ws + WS_OFFS);
    int* curs = (int*)(ws + WS_CURS);
    int* rowids = (int*)(ws + WS_ROWIDS);
    int pos = atomicAdd(&curs[fi], 1);
    rowids[offs[fi] + pos] = row;
}

// gather-sum per code (one wave per code, lane = dim) + fused finalize2.
__global__ __launch_bounds__(256) void vq_gather_kernel(
    const float* __restrict__ x,
    const float* __restrict__ embed_avg,
    const float* __restrict__ ws,
    float* __restrict__ out_embed) {
    const int lane = threadIdx.x & 63;
    const int k = blockIdx.x * 4 + (threadIdx.x >> 6);
    const int* counts = (const int*)(ws + WS_COUNTS);
    const int* offs = (const int*)(ws + WS_OFFS);
    const int* rowids = (const int*)(ws + WS_ROWIDS);

    const int cnt = counts[k];
    const int off = offs[k];
    float acc = 0.f;
    int i = 0;
    for (; i + 3 < cnt; i += 4) {
        int r0 = rowids[off + i + 0];
        int r1 = rowids[off + i + 1];
        int r2 = rowids[off + i + 2];
        int r3 = rowids[off + i + 3];
        float v0 = x[(size_t)r0 * DIM + lane];
        float v1 = x[(size_t)r1 * DIM + lane];
        float v2 = x[(size_t)r2 * DIM + lane];
        float v3 = x[(size_t)r3 * DIM + lane];
        acc += (v0 + v1) + (v2 + v3);
    }
    for (; i < cnt; ++i)
        acc += x[(size_t)rowids[off + i] * DIM + lane];

    float na = fmaf(OMD_F, acc, DECAY_F * embed_avg[(size_t)k * DIM + lane]);
    out_embed[(size_t)k * DIM + lane] = na / ws[WS_SMOOTH + k];
}

extern "C" void kernel_launch(void* const* d_in, const int* in_sizes, int n_in,
                              void* d_out, int out_size, void* d_ws, size_t ws_size,
                              hipStream_t stream) {
    const float* x            = (const float*)d_in[0];
    const float* embed        = (const float*)d_in[1];
    const float* embed_avg    = (const float*)d_in[2];
    const float* cluster_size = (const float*)d_in[3];

    float* out      = (float*)d_out;
    float* out_q    = out;                                  // [N*D]
    float* out_loss = out + (size_t)N_ROWS * DIM;           // [1]
    float* out_ind  = out_loss + 1;                         // [N]
    float* out_emb  = out_ind + N_ROWS;                     // [K*D]

    float* ws = (float*)d_ws;

    hipMemsetAsync(ws + WS_ZERO_BEG, 0, WS_ZERO_CNT * sizeof(float), stream);
    vq_e2_kernel<<<KC / 256, 256, 0, stream>>>(embed, ws);
    vq_main_kernel<<<(N_ROWS / 512) * 4, 256, 0, stream>>>(x, embed, ws);
    vq_combine_kernel<<<N_ROWS / 64, 256, 0, stream>>>(x, embed, ws, out_q, out_ind);
    vq_prefix_kernel<<<1, 256, 0, stream>>>(cluster_size, ws, out_loss);
    vq_fill_kernel<<<N_ROWS / 256, 256, 0, stream>>>(out_ind, ws);
    vq_gather_kernel<<<KC / 4, 256, 0, stream>>>(x, embed_avg, ws, out_emb);
}